// Round 1
// baseline (1928.321 us; speedup 1.0000x reference)
//
#include <hip/hip_runtime.h>
#include <math.h>

// QMixtralAttention — fp32 in/out (runtime-detected, bf16 fallback).
// Numerics: integer-exact quantized GEMMs (bf16-int MFMA, per-partition scale
// fold), split-bf16 (hi+lo) flash attention, fp32 attention output.
// R1: XOR-swizzled K/V LDS tiles in attn_k (16-way bank conflict -> 2-way),
//     swizzle applied via pre-swizzled global source (rule #21) since
//     global_load_lds writes linearly; + s_setprio around MFMA clusters.

typedef unsigned short u16;
typedef __bf16 bf16x8 __attribute__((ext_vector_type(8)));
typedef float f32x4 __attribute__((ext_vector_type(4)));

#define S_ 2048
#define NEG_BIG (-1e30f)

__device__ __forceinline__ float bf2f(u16 u) {
  union { unsigned int i; float f; } w; w.i = ((unsigned int)u) << 16; return w.f;
}
__device__ __forceinline__ u16 f2bf(float f) {
  union { float f; unsigned int i; } w; w.f = f;
  unsigned int i = w.i;
  i += ((i >> 16) & 1u) + 0x7fffu;  // RNE
  return (u16)(i >> 16);
}
// flag: 0 = bf16 input, 1 = fp32 input
__device__ __forceinline__ float loadf(const void* X, size_t j, int flag) {
  return flag ? ((const float*)X)[j] : bf2f(((const u16*)X)[j]);
}

#define GLDS16(g, l) __builtin_amdgcn_global_load_lds( \
    (__attribute__((address_space(1))) void*)(g),      \
    (__attribute__((address_space(3))) void*)(l), 16, 0, 0)

__global__ void detect_k(const u16* __restrict__ cosRaw, int* __restrict__ flag) {
  if (threadIdx.x == 0) *flag = (cosRaw[0] == 0x3F80u) ? 0 : 1;
}

// ---------------------------------------------------------------------------
// Quantize + permute: Y[row][j] = clip(rint(X[row][idx[j]]/s_p)) as bf16 INT,
// scales written to Sout[row*3+p]. Partitions: [0,3328) q7, [3328,3840) q31,
// [3840,4096) q127.
// ---------------------------------------------------------------------------
__device__ __forceinline__ float block_max(float x, float* sred, int t) {
#pragma unroll
  for (int o = 32; o > 0; o >>= 1) x = fmaxf(x, __shfl_xor(x, o));
  __syncthreads();
  if ((t & 63) == 0) sred[t >> 6] = x;
  __syncthreads();
  return fmaxf(fmaxf(sred[0], sred[1]), fmaxf(sred[2], sred[3]));
}

__global__ __launch_bounds__(256) void quant_permute_k(
    const void* __restrict__ X, const int* __restrict__ idx, u16* __restrict__ Y,
    float* __restrict__ Sout, const int* __restrict__ flagp, int mode /*1=force fp32*/)
{
  int flag = mode ? 1 : *flagp;
  int row = blockIdx.x;
  int t = threadIdx.x;
  size_t base = (size_t)row * 4096;
  u16* yr = Y + base;
  float v[16];
#pragma unroll
  for (int i = 0; i < 16; i++) v[i] = loadf(X, base + idx[i * 256 + t], flag);
  float m0 = 0.f;
#pragma unroll
  for (int i = 0; i < 13; i++) m0 = fmaxf(m0, fabsf(v[i]));
  float m1 = fmaxf(fabsf(v[13]), fabsf(v[14]));
  float m2 = fabsf(v[15]);
  __shared__ float sred[4];
  float M0 = block_max(m0, sred, t);
  float M1 = block_max(m1, sred, t);
  float M2 = block_max(m2, sred, t);
  float s0 = M0 / 7.f + 1e-8f;
  float s1 = M1 / 31.f + 1e-8f;
  float s2 = M2 / 127.f + 1e-8f;
#pragma unroll
  for (int i = 0; i < 16; i++) {
    float s, qm;
    if (i < 13)      { s = s0; qm = 7.f; }
    else if (i < 15) { s = s1; qm = 31.f; }
    else             { s = s2; qm = 127.f; }
    float q = rintf(v[i] / s);
    q = fminf(fmaxf(q, -qm), qm);
    yr[i * 256 + t] = f2bf(q);   // small integer: exact in bf16
  }
  if (t == 0) { Sout[row * 3] = s0; Sout[row * 3 + 1] = s1; Sout[row * 3 + 2] = s2; }
}

// ---------------------------------------------------------------------------
// Integer GEMM core: C[M][N] += sum_p Sa[m,p]*Sb[n,p]*(Aint_p · Bint_p^T)
// 128x128 tile, BK=64, phases of 52/8/4 BK-iters (partition boundaries).
// ropemap=1 remaps wave columns to {0-31,64-95}/{32-63,96-127} for RoPE pairs.
// ---------------------------------------------------------------------------
__device__ __forceinline__ int colbase_of(int wave, int ni, int ropemap) {
  return ropemap ? (((wave >> 1) << 5) + ((ni & 1) << 4) + ((ni >> 1) << 6))
                 : (((wave >> 1) << 6) + (ni << 4));
}

__device__ __forceinline__ void gemm_core(
    const u16* __restrict__ A, const u16* __restrict__ Bm,
    const float* __restrict__ Sa, const float* __restrict__ Sb,
    int bm, int bn, int tid, int ropemap,
    u16* As, u16* Bs, f32x4 C[4][4])
{
  int wave = tid >> 6, lane = tid & 63;
  int l15 = lane & 15, quad = lane >> 4;
  int wm = (wave & 1) << 6;
  const u16* Ag = A + (size_t)(bm * 128 + wave * 32 + (lane >> 3)) * 4096 + ((lane & 7) << 3);
  const u16* Bg = Bm + (size_t)(bn * 128 + wave * 32 + (lane >> 3)) * 4096 + ((lane & 7) << 3);
  u16* AsW = As + wave * 32 * 64;
  u16* BsW = Bs + wave * 32 * 64;
  f32x4 acc[4][4] = {};
  int cb[4];
#pragma unroll
  for (int ni = 0; ni < 4; ni++) cb[ni] = colbase_of(wave, ni, ropemap);
  int k0 = 0;
#pragma unroll 1
  for (int p = 0; p < 3; p++) {
    int iters = (p == 0) ? 52 : (p == 1 ? 8 : 4);
#pragma unroll 1
    for (int it = 0; it < iters; it++, k0 += 64) {
#pragma unroll
      for (int i = 0; i < 4; i++) {
        GLDS16(Ag + k0 + (size_t)(i * 8) * 4096, AsW + i * 8 * 64);
        GLDS16(Bg + k0 + (size_t)(i * 8) * 4096, BsW + i * 8 * 64);
      }
      __syncthreads();
#pragma unroll
      for (int kk = 0; kk < 2; kk++) {
        bf16x8 af[4], bfv[4];
#pragma unroll
        for (int mi = 0; mi < 4; mi++)
          af[mi] = *(const bf16x8*)(As + (wm + mi * 16 + l15) * 64 + kk * 32 + quad * 8);
#pragma unroll
        for (int ni = 0; ni < 4; ni++)
          bfv[ni] = *(const bf16x8*)(Bs + (cb[ni] + l15) * 64 + kk * 32 + quad * 8);
#pragma unroll
        for (int mi = 0; mi < 4; mi++)
#pragma unroll
          for (int ni = 0; ni < 4; ni++)
            acc[mi][ni] = __builtin_amdgcn_mfma_f32_16x16x32_bf16(af[mi], bfv[ni], acc[mi][ni], 0, 0, 0);
      }
      __syncthreads();
    }
    float sb[4];
#pragma unroll
    for (int ni = 0; ni < 4; ni++) sb[ni] = Sb[(size_t)(bn * 128 + cb[ni] + l15) * 3 + p];
#pragma unroll
    for (int mi = 0; mi < 4; mi++)
#pragma unroll
      for (int r = 0; r < 4; r++) {
        float sa = Sa[(size_t)(bm * 128 + wm + mi * 16 + quad * 4 + r) * 3 + p];
#pragma unroll
        for (int ni = 0; ni < 4; ni++) {
          C[mi][ni][r] += sa * sb[ni] * acc[mi][ni][r];
          acc[mi][ni][r] = 0.f;
        }
      }
  }
}

// GEMM + fused RoPE + scale + hi/lo split epilogue (Q and K projections).
__global__ __launch_bounds__(256) void gemm_rope_k(
    const u16* __restrict__ A, const u16* __restrict__ Bm,
    const float* __restrict__ Sa, const float* __restrict__ Sb,
    const void* __restrict__ Co, const void* __restrict__ Si,
    const int* __restrict__ flagp, u16* __restrict__ Qh, u16* __restrict__ Ql,
    int N, float scale)
{
  __shared__ __align__(16) u16 As[128 * 64];
  __shared__ __align__(16) u16 Bs[128 * 64];
  f32x4 C[4][4] = {};
  int tid = threadIdx.x;
  gemm_core(A, Bm, Sa, Sb, blockIdx.x, blockIdx.y, tid, 1, As, Bs, C);
  int wave = tid >> 6, lane = tid & 63, l15 = lane & 15, quad = lane >> 4;
  int wm = (wave & 1) << 6;
  int flag = *flagp;
#pragma unroll
  for (int mi = 0; mi < 4; mi++)
#pragma unroll
    for (int ni = 0; ni < 2; ni++) {
      int d1 = colbase_of(wave, ni, 1) + l15;  // < 64
#pragma unroll
      for (int r = 0; r < 4; r++) {
        int row = blockIdx.x * 128 + wm + mi * 16 + quad * 4 + r;
        float x1 = C[mi][ni][r], x2 = C[mi][ni + 2][r];
        size_t ci = (size_t)row * 128 + d1;
        float c1 = loadf(Co, ci, flag),      s1 = loadf(Si, ci, flag);
        float c2 = loadf(Co, ci + 64, flag), s2 = loadf(Si, ci + 64, flag);
        float y1 = (x1 * c1 - x2 * s1) * scale;
        float y2 = (x2 * c2 + x1 * s2) * scale;
        size_t o1 = (size_t)row * N + blockIdx.y * 128 + d1;
        u16 h1 = f2bf(y1); Qh[o1] = h1; Ql[o1] = f2bf(y1 - bf2f(h1));
        u16 h2 = f2bf(y2); Qh[o1 + 64] = h2; Ql[o1 + 64] = f2bf(y2 - bf2f(h2));
      }
    }
}

// GEMM + fused transpose + hi/lo split epilogue (V projection).
__global__ __launch_bounds__(256) void gemm_vt_k(
    const u16* __restrict__ A, const u16* __restrict__ Bm,
    const float* __restrict__ Sa, const float* __restrict__ Sb,
    u16* __restrict__ Vh, u16* __restrict__ Vl)
{
  __shared__ __align__(16) u16 As[128 * 64];
  __shared__ __align__(16) u16 Bs[128 * 64];
  f32x4 C[4][4] = {};
  int tid = threadIdx.x;
  gemm_core(A, Bm, Sa, Sb, blockIdx.x, blockIdx.y, tid, 0, As, Bs, C);
  int wave = tid >> 6, lane = tid & 63, l15 = lane & 15, quad = lane >> 4;
  int wm = (wave & 1) << 6;
#pragma unroll
  for (int mi = 0; mi < 4; mi++)
#pragma unroll
    for (int ni = 0; ni < 4; ni++) {
      int c = blockIdx.y * 128 + colbase_of(wave, ni, 0) + l15;
#pragma unroll
      for (int r = 0; r < 4; r++) {
        int row = blockIdx.x * 128 + wm + mi * 16 + quad * 4 + r;
        int b = row >> 11, s = row & 2047;
        float v = C[mi][ni][r];
        size_t o = ((size_t)(b * 1024 + c)) * 2048 + s;
        u16 h = f2bf(v); Vh[o] = h; Vl[o] = f2bf(v - bf2f(h));
      }
    }
}

// GEMM + output write (fp32 or bf16 per detected flag).
__global__ __launch_bounds__(256) void gemm_out_k(
    const u16* __restrict__ A, const u16* __restrict__ Bm,
    const float* __restrict__ Sa, const float* __restrict__ Sb,
    const int* __restrict__ flagp, void* __restrict__ Cout)
{
  __shared__ __align__(16) u16 As[128 * 64];
  __shared__ __align__(16) u16 Bs[128 * 64];
  f32x4 C[4][4] = {};
  int tid = threadIdx.x;
  gemm_core(A, Bm, Sa, Sb, blockIdx.x, blockIdx.y, tid, 0, As, Bs, C);
  int wave = tid >> 6, lane = tid & 63, l15 = lane & 15, quad = lane >> 4;
  int wm = (wave & 1) << 6;
  int flag = *flagp;
#pragma unroll
  for (int mi = 0; mi < 4; mi++)
#pragma unroll
    for (int ni = 0; ni < 4; ni++) {
      int col = blockIdx.y * 128 + colbase_of(wave, ni, 0) + l15;
#pragma unroll
      for (int r = 0; r < 4; r++) {
        int row = blockIdx.x * 128 + wm + mi * 16 + quad * 4 + r;
        if (flag) ((float*)Cout)[(size_t)row * 4096 + col] = C[mi][ni][r];
        else      ((u16*)Cout)[(size_t)row * 4096 + col] = f2bf(C[mi][ni][r]);
      }
    }
}

// ---------------------------------------------------------------------------
// Causal flash attention, split-bf16 (3-term MFMA) QK^T and PV. O is fp32.
// LDS = 64 KiB; P tiles alias the K tiles (barrier-protected).
// K/V LDS tiles are XOR-swizzled: LDS[row][cc] = global[row][cc ^ ((row&7)<<3)]
// (u16 units, 16B slots). global_load_lds writes linearly, so the swizzle is
// applied by pre-swizzling the per-lane GLOBAL source column; every
// ds_read_b128 applies the same XOR ((l15&7)<<3 — row&7 == l15&7 on all read
// paths). This turns the 16-way row-stride-128B/256B bank conflict into a
// free 2-way access.
// ---------------------------------------------------------------------------
__global__ __launch_bounds__(256) void attn_k(
    const u16* __restrict__ Qh, const u16* __restrict__ Ql,
    const u16* __restrict__ Kh, const u16* __restrict__ Kl,
    const u16* __restrict__ Vh, const u16* __restrict__ Vl,
    float* __restrict__ O)
{
  __shared__ __align__(16) u16 Ksh[64 * 128];
  __shared__ __align__(16) u16 Ksl[64 * 128];
  __shared__ __align__(16) u16 Vsh[128 * 64];
  __shared__ __align__(16) u16 Vsl[128 * 64];
  int tid = threadIdx.x, wave = tid >> 6, lane = tid & 63;
  int l15 = lane & 15, quad = lane >> 4;
  int qb = blockIdx.x, h = blockIdx.y, b = blockIdx.z;
  int kvh = h >> 2;
  int q0 = qb * 64 + wave * 16;
  bf16x8 qfh[4], qfl[4];
  const u16* qrow = Qh + (size_t)(b * S_ + q0 + l15) * 4096 + h * 128 + quad * 8;
  const u16* qrol = Ql + (size_t)(b * S_ + q0 + l15) * 4096 + h * 128 + quad * 8;
#pragma unroll
  for (int c = 0; c < 4; c++) {
    qfh[c] = *(const bf16x8*)(qrow + c * 32);
    qfl[c] = *(const bf16x8*)(qrol + c * 32);
  }
  float m_i[4], l_i[4];
#pragma unroll
  for (int r = 0; r < 4; r++) { m_i[r] = NEG_BIG; l_i[r] = 0.f; }
  f32x4 oacc[8] = {};
  // Staging rows this lane writes (LDS dest linear: base + lane*16B):
  //   K: dest row = wave*4 + i*16 + (lane>>4), col u16 = l15*8
  //   V: dest row = wave*8 + i*32 + (lane>>3), col u16 = (lane&7)*8
  // row&7 is i-invariant for both -> per-lane-constant source XOR.
  int krow = wave * 4 + (lane >> 4);
  int vrow = lane >> 3;  // 0..7
  size_t koff = (size_t)(b * S_ + krow) * 1024 + kvh * 128
              + ((l15 * 8) ^ ((krow & 7) << 3));
  size_t voff = ((size_t)(b * 1024 + kvh * 128 + wave * 8 + vrow)) * 2048
              + ((((lane & 7) ^ vrow)) << 3);
  const u16* Kgh = Kh + koff;
  const u16* Kgl = Kl + koff;
  const u16* Vgh = Vh + voff;
  const u16* Vgl = Vl + voff;
  u16* KshW = Ksh + wave * 4 * 128;
  u16* KslW = Ksl + wave * 4 * 128;
  u16* VshW = Vsh + wave * 8 * 64;
  u16* VslW = Vsl + wave * 8 * 64;
  u16* Ph = Ksh + wave * 1152;  // P tiles alias K tiles after barrier
  u16* Pl = Ksl + wave * 1152;
  int swz = (l15 & 7) << 3;     // read-side XOR (u16 units)
  int nk = qb * 64 + 64;
  for (int k0 = 0; k0 < nk; k0 += 64) {
#pragma unroll
    for (int i = 0; i < 4; i++) {
      GLDS16(Kgh + (size_t)(k0 + i * 16) * 1024, KshW + i * 16 * 128);
      GLDS16(Kgl + (size_t)(k0 + i * 16) * 1024, KslW + i * 16 * 128);
      GLDS16(Vgh + (size_t)(i * 32) * 2048 + k0, VshW + i * 32 * 64);
      GLDS16(Vgl + (size_t)(i * 32) * 2048 + k0, VslW + i * 32 * 64);
    }
    __syncthreads();
    f32x4 sacc[4] = {};
    __builtin_amdgcn_s_setprio(1);
#pragma unroll
    for (int c = 0; c < 4; c++) {
#pragma unroll
      for (int nt = 0; nt < 4; nt++) {
        int off = (nt * 16 + l15) * 128 + ((c * 32 + quad * 8) ^ swz);
        bf16x8 kh = *(const bf16x8*)(Ksh + off);
        bf16x8 kl = *(const bf16x8*)(Ksl + off);
        sacc[nt] = __builtin_amdgcn_mfma_f32_16x16x32_bf16(qfh[c], kh, sacc[nt], 0, 0, 0);
        sacc[nt] = __builtin_amdgcn_mfma_f32_16x16x32_bf16(qfh[c], kl, sacc[nt], 0, 0, 0);
        sacc[nt] = __builtin_amdgcn_mfma_f32_16x16x32_bf16(qfl[c], kh, sacc[nt], 0, 0, 0);
      }
    }
    __builtin_amdgcn_s_setprio(0);
    float p[4][4], alpha[4];
#pragma unroll
    for (int r = 0; r < 4; r++) {
      int qg = q0 + quad * 4 + r;
      float mr = m_i[r];
#pragma unroll
      for (int nt = 0; nt < 4; nt++) {
        int kg = k0 + nt * 16 + l15;
        float sv = (kg <= qg) ? sacc[nt][r] : NEG_BIG;
        sacc[nt][r] = sv;
        mr = fmaxf(mr, sv);
      }
#pragma unroll
      for (int o = 8; o > 0; o >>= 1) mr = fmaxf(mr, __shfl_xor(mr, o));
      float a = __expf(m_i[r] - mr);
      alpha[r] = a;
      float ps = 0.f;
#pragma unroll
      for (int nt = 0; nt < 4; nt++) {
        float pv = __expf(sacc[nt][r] - mr);
        p[nt][r] = pv;
        ps += pv;
      }
#pragma unroll
      for (int o = 8; o > 0; o >>= 1) ps += __shfl_xor(ps, o);
      l_i[r] = l_i[r] * a + ps;
      m_i[r] = mr;
    }
#pragma unroll
    for (int dt = 0; dt < 8; dt++)
#pragma unroll
      for (int r = 0; r < 4; r++) oacc[dt][r] *= alpha[r];
    __syncthreads();  // all waves done reading K tiles -> safe to alias with P
#pragma unroll
    for (int nt = 0; nt < 4; nt++)
#pragma unroll
      for (int r = 0; r < 4; r++) {
        float pv = p[nt][r];
        u16 ph = f2bf(pv);
        int o = (quad * 4 + r) * 72 + nt * 16 + l15;
        Ph[o] = ph;
        Pl[o] = f2bf(pv - bf2f(ph));
      }
#pragma unroll
    for (int kt = 0; kt < 2; kt++) {
      bf16x8 pfh = *(const bf16x8*)(Ph + l15 * 72 + kt * 32 + quad * 8);
      bf16x8 pfl = *(const bf16x8*)(Pl + l15 * 72 + kt * 32 + quad * 8);
      __builtin_amdgcn_s_setprio(1);
#pragma unroll
      for (int dt = 0; dt < 8; dt++) {
        int off = (dt * 16 + l15) * 64 + ((kt * 32 + quad * 8) ^ swz);
        bf16x8 vh = *(const bf16x8*)(Vsh + off);
        bf16x8 vl = *(const bf16x8*)(Vsl + off);
        oacc[dt] = __builtin_amdgcn_mfma_f32_16x16x32_bf16(pfh, vh, oacc[dt], 0, 0, 0);
        oacc[dt] = __builtin_amdgcn_mfma_f32_16x16x32_bf16(pfh, vl, oacc[dt], 0, 0, 0);
        oacc[dt] = __builtin_amdgcn_mfma_f32_16x16x32_bf16(pfl, vh, oacc[dt], 0, 0, 0);
      }
      __builtin_amdgcn_s_setprio(0);
    }
    __syncthreads();
  }
#pragma unroll
  for (int dt = 0; dt < 8; dt++)
#pragma unroll
    for (int r = 0; r < 4; r++) {
      int qg = q0 + quad * 4 + r;
      float ov = oacc[dt][r] / fmaxf(l_i[r], 1e-30f);
      O[(size_t)(b * S_ + qg) * 4096 + h * 128 + dt * 16 + l15] = ov;
    }
}

// ---------------------------------------------------------------------------
extern "C" void kernel_launch(void* const* d_in, const int* in_sizes, int n_in,
                              void* d_out, int out_size, void* d_ws, size_t ws_size,
                              hipStream_t stream)
{
  const void* hidden = d_in[0];
  const void* cosT   = d_in[1];
  const void* sinT   = d_in[2];
  const void* Wq     = d_in[3];
  const void* Wk     = d_in[4];
  const void* Wv     = d_in[5];
  const void* Wo     = d_in[6];
  const int* idx_q  = (const int*)d_in[7];
  const int* idx_k  = (const int*)d_in[8];
  const int* idx_v  = (const int*)d_in[9];
  const int* idx_o  = (const int*)d_in[10];

  char* ws = (char*)d_ws;
  const size_t MB = 1048576;
  int*   flag = (int*)ws;
  float* Sa   = (float*)(ws + MB);            // 48 KiB
  float* Sb   = (float*)(ws + MB + 512 * 1024);
  u16* Xi  = (u16*)(ws + 2 * MB);    // 32 MiB (A-int)
  u16* Wi  = (u16*)(ws + 34 * MB);   // 32 MiB (B-int)
  u16* Khi = (u16*)(ws + 66 * MB);   // 8
  u16* Klo = (u16*)(ws + 74 * MB);   // 8
  u16* Vhi = (u16*)(ws + 82 * MB);   // 8
  u16* Vlo = (u16*)(ws + 90 * MB);   // 8
  u16* Qhi = (u16*)(ws + 98 * MB);   // 32
  u16* Qlo = (u16*)(ws + 130 * MB);  // 32  (total 162 MiB)
  float* AO = (float*)(ws + 2 * MB); // 64, overlays Xi+Wi (dead by then)
  u16* Oq  = Qhi;   // overlays Q (dead after attention)
  u16* Woq = Qlo;

  detect_k<<<1, 64, 0, stream>>>((const u16*)cosT, flag);

  // K projection (+RoPE, split)
  quant_permute_k<<<4096, 256, 0, stream>>>(hidden, idx_k, Xi, Sa, flag, 0);
  quant_permute_k<<<1024, 256, 0, stream>>>(Wk, idx_k, Wi, Sb, flag, 0);
  gemm_rope_k<<<dim3(32, 8), 256, 0, stream>>>(Xi, Wi, Sa, Sb, cosT, sinT, flag, Khi, Klo, 1024, 1.0f);
  // V projection (+transpose, split)
  quant_permute_k<<<4096, 256, 0, stream>>>(hidden, idx_v, Xi, Sa, flag, 0);
  quant_permute_k<<<1024, 256, 0, stream>>>(Wv, idx_v, Wi, Sb, flag, 0);
  gemm_vt_k<<<dim3(32, 8), 256, 0, stream>>>(Xi, Wi, Sa, Sb, Vhi, Vlo);
  // Q projection (+RoPE+scale, split)
  quant_permute_k<<<4096, 256, 0, stream>>>(hidden, idx_q, Xi, Sa, flag, 0);
  quant_permute_k<<<4096, 256, 0, stream>>>(Wq, idx_q, Wi, Sb, flag, 0);
  gemm_rope_k<<<dim3(32, 32), 256, 0, stream>>>(Xi, Wi, Sa, Sb, cosT, sinT, flag, Qhi, Qlo, 4096, 0.08838834764831843f);
  // attention
  attn_k<<<dim3(32, 32, 2), 256, 0, stream>>>(Qhi, Qlo, Khi, Klo, Vhi, Vlo, AO);
  // output projection
  quant_permute_k<<<4096, 256, 0, stream>>>(AO, idx_o, Oq, Sa, flag, 1);
  quant_permute_k<<<4096, 256, 0, stream>>>(Wo, idx_o, Woq, Sb, flag, 0);
  gemm_out_k<<<dim3(32, 32), 256, 0, stream>>>(Oq, Woq, Sa, Sb, flag, d_out);
}